// Round 6
// baseline (167.418 us; speedup 1.0000x reference)
//
#include <hip/hip_runtime.h>

// LTCN layer: NB=64 blocks x K=64 neurons, BATCH=4096.
// R8: R7 + two-tile software pipeline per WG.
//  - R7 post-mortem: traffic minimal (FETCH 61MB, conflicts 0) but VALUBusy 28%,
//    occupancy 30% -> latency-bound serial chain per WG; 3 WG/CU co-stall.
//  - R8: each WG owns TWO 128-row batch tiles (grid 16x64=1024 WGs). Both
//    tiles' A-fragments are loaded BEFORE the barrier; tile bodies are fully
//    unrolled straight-line so the scheduler hoists tile-1 loads under
//    tile-0's tanh/GEMM/epilogue (~1500cy shadow). Staging + barrier cost
//    halved. Band WAR stays intra-wave (DS in-order) -> still ONE barrier.
//  - Watch VGPR: +16 for tile-1 frags; target <=84 (3 WG/CU). Spill signature
//    would be FETCH >> 62MB.

#define IN_DIM 256
#define K 64
#define NB 64
#define BATCH 4096
#define NTOT (NB * K)          // 4096
#define DTC 0.05f
#define TAU_EPS 1e-6f
#define NMATS 259              // 64 rec + 63 fwd + 64 El + 64 Elr + 4 Win chunks
#define WS_W_OFF 16384         // packed weights start after invTau f32[4096]
#define TPW 2                  // batch tiles per WG

typedef __bf16 bf16;
typedef bf16 bf16x8 __attribute__((ext_vector_type(8)));
typedef float f32x4 __attribute__((ext_vector_type(4)));

__device__ __forceinline__ float fast_tanh(float x) {
    float e = __expf(2.0f * x);
    return 1.0f - 2.0f * __builtin_amdgcn_rcpf(e + 1.0f);
}

// Load one 64-wide A-operand row slice (f32) into two bf16x8 fragments.
__device__ __forceinline__ void load_afrag(const float* __restrict__ rowp,
                                           bf16x8& f0, bf16x8& f1) {
    float4 a0 = *(const float4*)(rowp);
    float4 a1 = *(const float4*)(rowp + 4);
    float4 a2 = *(const float4*)(rowp + 32);
    float4 a3 = *(const float4*)(rowp + 36);
    f0 = (bf16x8){ (bf16)a0.x, (bf16)a0.y, (bf16)a0.z, (bf16)a0.w,
                   (bf16)a1.x, (bf16)a1.y, (bf16)a1.z, (bf16)a1.w };
    f1 = (bf16x8){ (bf16)a2.x, (bf16)a2.y, (bf16)a2.z, (bf16)a2.w,
                   (bf16)a3.x, (bf16)a3.y, (bf16)a3.z, (bf16)a3.w };
}

// ---------------- pre-pass: pack weights to B-fragment order + invTau ----------------
// Packed mat m (4096 bf16 = 8KB): element ((ct*2+kh)*64 + lane)*8 + e holds
// W[n = ct*16 + (lane&15)][k = kh*32 + (lane>>4)*8 + e]  (B-frag lane mapping).
__global__ __launch_bounds__(256)
void pack_kernel(const float* __restrict__ W_in_w, const float* __restrict__ W_fwd_w,
                 const float* __restrict__ W_rec_w, const float* __restrict__ E_l,
                 const float* __restrict__ E_l_r, const float* __restrict__ tau_raw,
                 void* __restrict__ ws) {
    int gid = blockIdx.x * 256 + threadIdx.x;
    float* invTau = (float*)ws;
    bf16* pw = (bf16*)((char*)ws + WS_W_OFF);
    if (gid < NMATS * 512) {
        int m    = gid >> 9;
        int r    = gid & 511;
        int ct   = r >> 7;
        int kh   = (r >> 6) & 1;
        int lane = r & 63;
        int n  = ct * 16 + (lane & 15);
        int k0 = kh * 32 + (lane >> 4) * 8;
        const float* src;
        if      (m < 64)  src = W_rec_w + (size_t)m * 4096         + n * 64  + k0;
        else if (m < 127) src = W_fwd_w + (size_t)(m - 64) * 4096  + n * 64  + k0;
        else if (m < 191) src = E_l     + (size_t)(m - 127) * 4096 + n * 64  + k0;
        else if (m < 255) src = E_l_r   + (size_t)(m - 191) * 4096 + n * 64  + k0;
        else              src = W_in_w  + (size_t)n * IN_DIM + (m - 255) * 64 + k0;
        float4 a = *(const float4*)src;
        float4 b = *(const float4*)(src + 4);
        bf16x8 o = { (bf16)a.x, (bf16)a.y, (bf16)a.z, (bf16)a.w,
                     (bf16)b.x, (bf16)b.y, (bf16)b.z, (bf16)b.w };
        *(bf16x8*)(pw + (size_t)gid * 8) = o;
    } else if (gid < NMATS * 512 + NTOT) {
        int i = gid - NMATS * 512;
        float x = tau_raw[i];
        float sp = (x > 15.0f) ? x : log1pf(__expf(x));
        invTau[i] = 1.0f / (sp + TAU_EPS);
    }
}

// ---------------- main kernel: 1 barrier, 2 pipelined tiles ----------------
__global__ __launch_bounds__(512, 4)
void ltcn_main(const float* __restrict__ y, const float* __restrict__ u_t,
               const float* __restrict__ W_in_b, const float* __restrict__ W_fwd_b,
               const float* __restrict__ W_rec_b, const void* __restrict__ ws,
               float* __restrict__ out) {
    __shared__ bf16 sW[4 * 4096];    // slots: 0=W_rec 1=W_fwd/Win0 2=El 3=Elr
    __shared__ bf16 sNet[8 * 1024];  // per-wave 16x64 swizzled net band

    const float* invTau = (const float*)ws;
    const bf16*  pw     = (const bf16*)((const char*)ws + WS_W_OFF);

    const int tid  = threadIdx.x;
    const int j    = blockIdx.y;
    const int wave = tid >> 6;
    const int lane = tid & 63;
    const int quad = lane >> 4;
    const int l16  = lane & 15;
    const int am   = wave * 16 + l16;
    const int boff = quad * 8;
    const int tile0 = blockIdx.x * TPW;

    // ---- A fragments for BOTH tiles + biases (issued before the barrier) ----
    bf16x8 yc0[TPW], yc1[TPW], yp0[TPW], yp1[TPW];
#pragma unroll
    for (int t = 0; t < TPW; ++t) {
        int b0 = (tile0 + t) * 128;
        load_afrag(y + (size_t)(b0 + am) * NTOT + j * K + boff, yc0[t], yc1[t]);
        if (j != 0) load_afrag(y + (size_t)(b0 + am) * NTOT + (j - 1) * K + boff, yp0[t], yp1[t]);
        else        load_afrag(u_t + (size_t)(b0 + am) * IN_DIM + boff, yp0[t], yp1[t]);
    }

    float brv[4], bfv[4], itv[4];
#pragma unroll
    for (int ct = 0; ct < 4; ++ct) {
        int n = ct * 16 + l16;
        brv[ct] = W_rec_b[j * K + n];
        itv[ct] = invTau[j * K + n];
        bfv[ct] = (j == 0) ? W_in_b[n] : W_fwd_b[(j - 1) * K + n];
    }

    // ---- cooperative stage: 4 x 16B memcpy per thread (packed -> LDS) ----
    {
        int m1 = (j != 0) ? (64 + j - 1) : 255;   // W_fwd or W_in chunk 0
        *(bf16x8*)(sW +    0     + tid * 8) = *(const bf16x8*)(pw + (size_t)j          * 4096 + tid * 8);
        *(bf16x8*)(sW + 1 * 4096 + tid * 8) = *(const bf16x8*)(pw + (size_t)m1         * 4096 + tid * 8);
        *(bf16x8*)(sW + 2 * 4096 + tid * 8) = *(const bf16x8*)(pw + (size_t)(127 + j)  * 4096 + tid * 8);
        *(bf16x8*)(sW + 3 * 4096 + tid * 8) = *(const bf16x8*)(pw + (size_t)(191 + j)  * 4096 + tid * 8);
    }
    __syncthreads();   // the ONLY barrier

    bf16* band = sNet + wave * 1024;          // 16 rows x 64 elems, swizzled
    const int sw = (l16 & 7) << 3;
    const bf16* a0p = band + l16 * 64 + ((boff     ) ^ sw);
    const bf16* a1p = band + l16 * 64 + ((32 + boff) ^ sw);

    // ---- two fully-unrolled tile bodies; scheduler interleaves them ----
#pragma unroll
    for (int t = 0; t < TPW; ++t) {
        const int b0 = (tile0 + t) * 128;

        // GEMM1: rec + fwd (B-frags: linear conflict-free ds_read_b128)
        f32x4 accR[4] = {}, accF[4] = {};
#pragma unroll
        for (int ct = 0; ct < 4; ++ct) {
            bf16x8 br0 = *(const bf16x8*)(sW +            ((ct * 2 + 0) * 64 + lane) * 8);
            bf16x8 br1 = *(const bf16x8*)(sW +            ((ct * 2 + 1) * 64 + lane) * 8);
            accR[ct] = __builtin_amdgcn_mfma_f32_16x16x32_bf16(yc0[t], br0, accR[ct], 0, 0, 0);
            accR[ct] = __builtin_amdgcn_mfma_f32_16x16x32_bf16(yc1[t], br1, accR[ct], 0, 0, 0);
            bf16x8 bf0 = *(const bf16x8*)(sW + 1 * 4096 + ((ct * 2 + 0) * 64 + lane) * 8);
            bf16x8 bf1 = *(const bf16x8*)(sW + 1 * 4096 + ((ct * 2 + 1) * 64 + lane) * 8);
            accF[ct] = __builtin_amdgcn_mfma_f32_16x16x32_bf16(yp0[t], bf0, accF[ct], 0, 0, 0);
            accF[ct] = __builtin_amdgcn_mfma_f32_16x16x32_bf16(yp1[t], bf1, accF[ct], 0, 0, 0);
        }
        if (j == 0) {   // W_in chunks 1..3: per-lane from L2 (16 of 1024 WGs)
#pragma unroll 1
            for (int kc = 1; kc < 4; ++kc) {
                bf16x8 u0, u1;
                load_afrag(u_t + (size_t)(b0 + am) * IN_DIM + kc * 64 + boff, u0, u1);
                const bf16* mwin = pw + (size_t)(255 + kc) * 4096;
#pragma unroll
                for (int ct = 0; ct < 4; ++ct) {
                    bf16x8 w0 = *(const bf16x8*)(mwin + ((ct * 2 + 0) * 64 + lane) * 8);
                    bf16x8 w1 = *(const bf16x8*)(mwin + ((ct * 2 + 1) * 64 + lane) * 8);
                    accF[ct] = __builtin_amdgcn_mfma_f32_16x16x32_bf16(u0, w0, accF[ct], 0, 0, 0);
                    accF[ct] = __builtin_amdgcn_mfma_f32_16x16x32_bf16(u1, w1, accF[ct], 0, 0, 0);
                }
            }
        }

        // tanh + decay (regs)
        float absum[4][4];
#pragma unroll
        for (int ct = 0; ct < 4; ++ct) {
#pragma unroll
            for (int r = 0; r < 4; ++r) {
                float no = fast_tanh(accF[ct][r] + bfv[ct]);
                float nr = fast_tanh(accR[ct][r] + brv[ct]);
                accF[ct][r] = no;
                accR[ct][r] = nr;
                absum[ct][r] = itv[ct] + fabsf(no) + fabsf(nr);
            }
        }

        // 4a: net_out -> swizzled band -> A-frags -> El MFMAs (intra-wave)
#pragma unroll
        for (int ct = 0; ct < 4; ++ct)
#pragma unroll
            for (int r = 0; r < 4; ++r) {
                int rr = quad * 4 + r;
                band[rr * 64 + ((ct * 16 + l16) ^ ((rr & 7) << 3))] = (bf16)accF[ct][r];
            }
        bf16x8 aO0 = *(const bf16x8*)a0p, aO1 = *(const bf16x8*)a1p;

        f32x4 accD[4] = {};
#pragma unroll
        for (int ct = 0; ct < 4; ++ct) {
            bf16x8 e0 = *(const bf16x8*)(sW + 2 * 4096 + ((ct * 2 + 0) * 64 + lane) * 8);
            bf16x8 e1 = *(const bf16x8*)(sW + 2 * 4096 + ((ct * 2 + 1) * 64 + lane) * 8);
            accD[ct] = __builtin_amdgcn_mfma_f32_16x16x32_bf16(aO0, e0, accD[ct], 0, 0, 0);
            accD[ct] = __builtin_amdgcn_mfma_f32_16x16x32_bf16(aO1, e1, accD[ct], 0, 0, 0);
        }

        // 4b: net_rec overwrites band (intra-wave WAR) -> Elr MFMAs
#pragma unroll
        for (int ct = 0; ct < 4; ++ct)
#pragma unroll
            for (int r = 0; r < 4; ++r) {
                int rr = quad * 4 + r;
                band[rr * 64 + ((ct * 16 + l16) ^ ((rr & 7) << 3))] = (bf16)accR[ct][r];
            }
        bf16x8 aR0 = *(const bf16x8*)a0p, aR1 = *(const bf16x8*)a1p;

        // ye re-read (L1-hot: same lines as yc loads) hides under Elr MFMAs
        float ye[4][4];
        const float* yep = y + (size_t)(b0 + wave * 16 + quad * 4) * NTOT + (size_t)j * K + l16;
#pragma unroll
        for (int ct = 0; ct < 4; ++ct)
#pragma unroll
            for (int r = 0; r < 4; ++r)
                ye[ct][r] = yep[(size_t)r * NTOT + ct * 16];

#pragma unroll
        for (int ct = 0; ct < 4; ++ct) {
            bf16x8 e0 = *(const bf16x8*)(sW + 3 * 4096 + ((ct * 2 + 0) * 64 + lane) * 8);
            bf16x8 e1 = *(const bf16x8*)(sW + 3 * 4096 + ((ct * 2 + 1) * 64 + lane) * 8);
            accD[ct] = __builtin_amdgcn_mfma_f32_16x16x32_bf16(aR0, e0, accD[ct], 0, 0, 0);
            accD[ct] = __builtin_amdgcn_mfma_f32_16x16x32_bf16(aR1, e1, accD[ct], 0, 0, 0);
        }

        // epilogue
#pragma unroll
        for (int ct = 0; ct < 4; ++ct) {
#pragma unroll
            for (int r = 0; r < 4; ++r) {
                size_t gi = (size_t)(b0 + wave * 16 + quad * 4 + r) * NTOT + j * K + ct * 16 + l16;
                out[gi] = (ye[ct][r] + DTC * accD[ct][r])
                          * __builtin_amdgcn_rcpf(1.0f + DTC * absum[ct][r]);
            }
        }
    }
}

extern "C" void kernel_launch(void* const* d_in, const int* in_sizes, int n_in,
                              void* d_out, int out_size, void* d_ws, size_t ws_size,
                              hipStream_t stream) {
    const float* y       = (const float*)d_in[0];
    const float* u_t     = (const float*)d_in[1];
    const float* tau_raw = (const float*)d_in[2];
    const float* W_in_w  = (const float*)d_in[3];
    const float* W_in_b  = (const float*)d_in[4];
    const float* W_fwd_w = (const float*)d_in[5];
    const float* W_fwd_b = (const float*)d_in[6];
    const float* W_rec_w = (const float*)d_in[7];
    const float* W_rec_b = (const float*)d_in[8];
    const float* E_l     = (const float*)d_in[9];
    const float* E_l_r   = (const float*)d_in[10];
    float* out = (float*)d_out;

    // pre-pass: pack weights (bf16 fragment order) + invTau into workspace
    int pack_threads = NMATS * 512 + NTOT;           // 136704
    hipLaunchKernelGGL(pack_kernel, dim3((pack_threads + 255) / 256), dim3(256),
                       0, stream,
                       W_in_w, W_fwd_w, W_rec_w, E_l, E_l_r, tau_raw, d_ws);

    dim3 grid(BATCH / (128 * TPW), NB);
    hipLaunchKernelGGL(ltcn_main, grid, dim3(512), 0, stream,
                       y, u_t, W_in_b, W_fwd_b, W_rec_b, d_ws, out);
}

// Round 7
// 159.319 us; speedup vs baseline: 1.0508x; 1.0508x over previous
//
#include <hip/hip_runtime.h>

// LTCN layer: NB=64 blocks x K=64 neurons, BATCH=4096.
// R9: R7 + band overlay onto dead weight slots -> 4 WG/CU.
//  - R8 post-mortem: holding 2 tiles' A-frags from entry spilled (FETCH/WRITE
//    +34MB scratch, dur 63us). Reverted to R7 structure (TPW=1).
//  - R7 residual: 3 WG/CU (LDS 49152), everything <30% busy, latency-bound.
//  - R9: sW slots 0/1 (W_rec/W_fwd, 16KB) are DEAD after GEMM1; the per-wave
//    net bands overlay them. sNet deleted -> LDS 32768 -> 4 WG/CU = 32
//    waves/CU (HW wave-slot max). VGPR untouched (~52; 8 waves/SIMD fine).
//  - Cost: one extra __syncthreads (WAR on slots 0/1), placed AFTER tanh so
//    every wave arrives post-VALU-burst with its LDS reads long done ->
//    arrival skew absorbed, barrier cheap. (R5's overlay failed pre-pack and
//    pre-drive-split; both confounds are gone now.)
//  - launch_bounds stays (512,4): allocator relaxed (no R4-style forced spill);
//    runtime residency is LDS/wave-slot limited, not allocator limited.

#define IN_DIM 256
#define K 64
#define NB 64
#define BATCH 4096
#define NTOT (NB * K)          // 4096
#define DTC 0.05f
#define TAU_EPS 1e-6f
#define NMATS 259              // 64 rec + 63 fwd + 64 El + 64 Elr + 4 Win chunks
#define WS_W_OFF 16384         // packed weights start after invTau f32[4096]

typedef __bf16 bf16;
typedef bf16 bf16x8 __attribute__((ext_vector_type(8)));
typedef float f32x4 __attribute__((ext_vector_type(4)));

__device__ __forceinline__ float fast_tanh(float x) {
    float e = __expf(2.0f * x);
    return 1.0f - 2.0f * __builtin_amdgcn_rcpf(e + 1.0f);
}

// Load one 64-wide A-operand row slice (f32) into two bf16x8 fragments.
__device__ __forceinline__ void load_afrag(const float* __restrict__ rowp,
                                           bf16x8& f0, bf16x8& f1) {
    float4 a0 = *(const float4*)(rowp);
    float4 a1 = *(const float4*)(rowp + 4);
    float4 a2 = *(const float4*)(rowp + 32);
    float4 a3 = *(const float4*)(rowp + 36);
    f0 = (bf16x8){ (bf16)a0.x, (bf16)a0.y, (bf16)a0.z, (bf16)a0.w,
                   (bf16)a1.x, (bf16)a1.y, (bf16)a1.z, (bf16)a1.w };
    f1 = (bf16x8){ (bf16)a2.x, (bf16)a2.y, (bf16)a2.z, (bf16)a2.w,
                   (bf16)a3.x, (bf16)a3.y, (bf16)a3.z, (bf16)a3.w };
}

// ---------------- pre-pass: pack weights to B-fragment order + invTau ----------------
// Packed mat m (4096 bf16 = 8KB): element ((ct*2+kh)*64 + lane)*8 + e holds
// W[n = ct*16 + (lane&15)][k = kh*32 + (lane>>4)*8 + e]  (B-frag lane mapping).
__global__ __launch_bounds__(256)
void pack_kernel(const float* __restrict__ W_in_w, const float* __restrict__ W_fwd_w,
                 const float* __restrict__ W_rec_w, const float* __restrict__ E_l,
                 const float* __restrict__ E_l_r, const float* __restrict__ tau_raw,
                 void* __restrict__ ws) {
    int gid = blockIdx.x * 256 + threadIdx.x;
    float* invTau = (float*)ws;
    bf16* pw = (bf16*)((char*)ws + WS_W_OFF);
    if (gid < NMATS * 512) {
        int m    = gid >> 9;
        int r    = gid & 511;
        int ct   = r >> 7;
        int kh   = (r >> 6) & 1;
        int lane = r & 63;
        int n  = ct * 16 + (lane & 15);
        int k0 = kh * 32 + (lane >> 4) * 8;
        const float* src;
        if      (m < 64)  src = W_rec_w + (size_t)m * 4096         + n * 64  + k0;
        else if (m < 127) src = W_fwd_w + (size_t)(m - 64) * 4096  + n * 64  + k0;
        else if (m < 191) src = E_l     + (size_t)(m - 127) * 4096 + n * 64  + k0;
        else if (m < 255) src = E_l_r   + (size_t)(m - 191) * 4096 + n * 64  + k0;
        else              src = W_in_w  + (size_t)n * IN_DIM + (m - 255) * 64 + k0;
        float4 a = *(const float4*)src;
        float4 b = *(const float4*)(src + 4);
        bf16x8 o = { (bf16)a.x, (bf16)a.y, (bf16)a.z, (bf16)a.w,
                     (bf16)b.x, (bf16)b.y, (bf16)b.z, (bf16)b.w };
        *(bf16x8*)(pw + (size_t)gid * 8) = o;
    } else if (gid < NMATS * 512 + NTOT) {
        int i = gid - NMATS * 512;
        float x = tau_raw[i];
        float sp = (x > 15.0f) ? x : log1pf(__expf(x));
        invTau[i] = 1.0f / (sp + TAU_EPS);
    }
}

// ---------------- main kernel: 2 barriers, band overlays dead weight slots ----------------
__global__ __launch_bounds__(512, 4)
void ltcn_main(const float* __restrict__ y, const float* __restrict__ u_t,
               const float* __restrict__ W_in_b, const float* __restrict__ W_fwd_b,
               const float* __restrict__ W_rec_b, const void* __restrict__ ws,
               float* __restrict__ out) {
    __shared__ bf16 sW[4 * 4096];    // slots: 0=W_rec 1=W_fwd/Win0 2=El 3=Elr
                                     // slots 0+1 reused as 8x 2KB net bands

    const float* invTau = (const float*)ws;
    const bf16*  pw     = (const bf16*)((const char*)ws + WS_W_OFF);

    const int tid  = threadIdx.x;
    const int j    = blockIdx.y;
    const int b0   = blockIdx.x * 128;
    const int wave = tid >> 6;
    const int lane = tid & 63;
    const int quad = lane >> 4;
    const int l16  = lane & 15;
    const int am   = wave * 16 + l16;
    const int boff = quad * 8;

    // ---- A fragments + biases (global, issued up front) ----
    bf16x8 yc0, yc1, yp0, yp1;
    load_afrag(y + (size_t)(b0 + am) * NTOT + j * K + boff, yc0, yc1);
    if (j != 0) load_afrag(y + (size_t)(b0 + am) * NTOT + (j - 1) * K + boff, yp0, yp1);
    else        load_afrag(u_t + (size_t)(b0 + am) * IN_DIM + boff, yp0, yp1);

    float brv[4], bfv[4], itv[4];
#pragma unroll
    for (int ct = 0; ct < 4; ++ct) {
        int n = ct * 16 + l16;
        brv[ct] = W_rec_b[j * K + n];
        itv[ct] = invTau[j * K + n];
        bfv[ct] = (j == 0) ? W_in_b[n] : W_fwd_b[(j - 1) * K + n];
    }

    // ---- cooperative stage: 4 x 16B memcpy per thread (packed -> LDS) ----
    {
        int m1 = (j != 0) ? (64 + j - 1) : 255;   // W_fwd or W_in chunk 0
        *(bf16x8*)(sW +    0     + tid * 8) = *(const bf16x8*)(pw + (size_t)j          * 4096 + tid * 8);
        *(bf16x8*)(sW + 1 * 4096 + tid * 8) = *(const bf16x8*)(pw + (size_t)m1         * 4096 + tid * 8);
        *(bf16x8*)(sW + 2 * 4096 + tid * 8) = *(const bf16x8*)(pw + (size_t)(127 + j)  * 4096 + tid * 8);
        *(bf16x8*)(sW + 3 * 4096 + tid * 8) = *(const bf16x8*)(pw + (size_t)(191 + j)  * 4096 + tid * 8);
    }
    __syncthreads();   // barrier #1: weights staged

    // ---- GEMM1: rec + fwd, B-frags = linear conflict-free ds_read_b128 ----
    f32x4 accR[4] = {}, accF[4] = {};
#pragma unroll
    for (int ct = 0; ct < 4; ++ct) {
        bf16x8 br0 = *(const bf16x8*)(sW +            ((ct * 2 + 0) * 64 + lane) * 8);
        bf16x8 br1 = *(const bf16x8*)(sW +            ((ct * 2 + 1) * 64 + lane) * 8);
        accR[ct] = __builtin_amdgcn_mfma_f32_16x16x32_bf16(yc0, br0, accR[ct], 0, 0, 0);
        accR[ct] = __builtin_amdgcn_mfma_f32_16x16x32_bf16(yc1, br1, accR[ct], 0, 0, 0);
        bf16x8 bf0 = *(const bf16x8*)(sW + 1 * 4096 + ((ct * 2 + 0) * 64 + lane) * 8);
        bf16x8 bf1 = *(const bf16x8*)(sW + 1 * 4096 + ((ct * 2 + 1) * 64 + lane) * 8);
        accF[ct] = __builtin_amdgcn_mfma_f32_16x16x32_bf16(yp0, bf0, accF[ct], 0, 0, 0);
        accF[ct] = __builtin_amdgcn_mfma_f32_16x16x32_bf16(yp1, bf1, accF[ct], 0, 0, 0);
    }
    if (j == 0) {     // W_in chunks 1..3: per-lane from L2 (32 of 2048 WGs only)
#pragma unroll 1
        for (int kc = 1; kc < 4; ++kc) {
            bf16x8 u0, u1;
            load_afrag(u_t + (size_t)(b0 + am) * IN_DIM + kc * 64 + boff, u0, u1);
            const bf16* mwin = pw + (size_t)(255 + kc) * 4096;
#pragma unroll
            for (int ct = 0; ct < 4; ++ct) {
                bf16x8 w0 = *(const bf16x8*)(mwin + ((ct * 2 + 0) * 64 + lane) * 8);
                bf16x8 w1 = *(const bf16x8*)(mwin + ((ct * 2 + 1) * 64 + lane) * 8);
                accF[ct] = __builtin_amdgcn_mfma_f32_16x16x32_bf16(u0, w0, accF[ct], 0, 0, 0);
                accF[ct] = __builtin_amdgcn_mfma_f32_16x16x32_bf16(u1, w1, accF[ct], 0, 0, 0);
            }
        }
    }

    // ---- tanh + decay (regs) — long VALU phase absorbs barrier-arrival skew ----
    float absum[4][4];
#pragma unroll
    for (int ct = 0; ct < 4; ++ct) {
#pragma unroll
        for (int r = 0; r < 4; ++r) {
            float no = fast_tanh(accF[ct][r] + bfv[ct]);
            float nr = fast_tanh(accR[ct][r] + brv[ct]);
            accF[ct][r] = no;
            accR[ct][r] = nr;
            absum[ct][r] = itv[ct] + fabsf(no) + fabsf(nr);
        }
    }

    __syncthreads();   // barrier #2: WAR — all waves' GEMM1 reads of slots 0/1
                       // completed (data-dep before tanh); bands may now overlay

    // ---- per-wave swizzled net band overlaying slots 0/1 (intra-wave only) ----
    bf16* band = sW + wave * 1024;            // 16 rows x 64 elems, swizzled
    const int sw = (l16 & 7) << 3;
    const bf16* a0p = band + l16 * 64 + ((boff     ) ^ sw);
    const bf16* a1p = band + l16 * 64 + ((32 + boff) ^ sw);

    // 4a: net_out -> band -> A-frags -> El MFMAs
#pragma unroll
    for (int ct = 0; ct < 4; ++ct)
#pragma unroll
        for (int r = 0; r < 4; ++r) {
            int rr = quad * 4 + r;
            band[rr * 64 + ((ct * 16 + l16) ^ ((rr & 7) << 3))] = (bf16)accF[ct][r];
        }
    bf16x8 aO0 = *(const bf16x8*)a0p, aO1 = *(const bf16x8*)a1p;

    f32x4 accD[4] = {};
#pragma unroll
    for (int ct = 0; ct < 4; ++ct) {
        bf16x8 e0 = *(const bf16x8*)(sW + 2 * 4096 + ((ct * 2 + 0) * 64 + lane) * 8);
        bf16x8 e1 = *(const bf16x8*)(sW + 2 * 4096 + ((ct * 2 + 1) * 64 + lane) * 8);
        accD[ct] = __builtin_amdgcn_mfma_f32_16x16x32_bf16(aO0, e0, accD[ct], 0, 0, 0);
        accD[ct] = __builtin_amdgcn_mfma_f32_16x16x32_bf16(aO1, e1, accD[ct], 0, 0, 0);
    }

    // 4b: net_rec overwrites band (intra-wave WAR, DS in-order) -> Elr MFMAs
#pragma unroll
    for (int ct = 0; ct < 4; ++ct)
#pragma unroll
        for (int r = 0; r < 4; ++r) {
            int rr = quad * 4 + r;
            band[rr * 64 + ((ct * 16 + l16) ^ ((rr & 7) << 3))] = (bf16)accR[ct][r];
        }
    bf16x8 aR0 = *(const bf16x8*)a0p, aR1 = *(const bf16x8*)a1p;

    // ye re-read (L2-hot) hides under the Elr MFMAs
    float ye[4][4];
    const float* yep = y + (size_t)(b0 + wave * 16 + quad * 4) * NTOT + (size_t)j * K + l16;
#pragma unroll
    for (int ct = 0; ct < 4; ++ct)
#pragma unroll
        for (int r = 0; r < 4; ++r)
            ye[ct][r] = yep[(size_t)r * NTOT + ct * 16];

#pragma unroll
    for (int ct = 0; ct < 4; ++ct) {
        bf16x8 e0 = *(const bf16x8*)(sW + 3 * 4096 + ((ct * 2 + 0) * 64 + lane) * 8);
        bf16x8 e1 = *(const bf16x8*)(sW + 3 * 4096 + ((ct * 2 + 1) * 64 + lane) * 8);
        accD[ct] = __builtin_amdgcn_mfma_f32_16x16x32_bf16(aR0, e0, accD[ct], 0, 0, 0);
        accD[ct] = __builtin_amdgcn_mfma_f32_16x16x32_bf16(aR1, e1, accD[ct], 0, 0, 0);
    }

    // ---- epilogue ----
#pragma unroll
    for (int ct = 0; ct < 4; ++ct) {
#pragma unroll
        for (int r = 0; r < 4; ++r) {
            size_t gi = (size_t)(b0 + wave * 16 + quad * 4 + r) * NTOT + j * K + ct * 16 + l16;
            out[gi] = (ye[ct][r] + DTC * accD[ct][r])
                      * __builtin_amdgcn_rcpf(1.0f + DTC * absum[ct][r]);
        }
    }
}

extern "C" void kernel_launch(void* const* d_in, const int* in_sizes, int n_in,
                              void* d_out, int out_size, void* d_ws, size_t ws_size,
                              hipStream_t stream) {
    const float* y       = (const float*)d_in[0];
    const float* u_t     = (const float*)d_in[1];
    const float* tau_raw = (const float*)d_in[2];
    const float* W_in_w  = (const float*)d_in[3];
    const float* W_in_b  = (const float*)d_in[4];
    const float* W_fwd_w = (const float*)d_in[5];
    const float* W_fwd_b = (const float*)d_in[6];
    const float* W_rec_w = (const float*)d_in[7];
    const float* W_rec_b = (const float*)d_in[8];
    const float* E_l     = (const float*)d_in[9];
    const float* E_l_r   = (const float*)d_in[10];
    float* out = (float*)d_out;

    // pre-pass: pack weights (bf16 fragment order) + invTau into workspace
    int pack_threads = NMATS * 512 + NTOT;           // 136704
    hipLaunchKernelGGL(pack_kernel, dim3((pack_threads + 255) / 256), dim3(256),
                       0, stream,
                       W_in_w, W_fwd_w, W_rec_w, E_l, E_l_r, tau_raw, d_ws);

    dim3 grid(BATCH / 128, NB);
    hipLaunchKernelGGL(ltcn_main, grid, dim3(512), 0, stream,
                       y, u_t, W_in_b, W_fwd_b, W_rec_b, d_ws, out);
}